// Round 2
// baseline (271.290 us; speedup 1.0000x reference)
//
#include <hip/hip_runtime.h>
#include <hip/hip_bf16.h>

#define CAP 8
#define EPSF 1e-8f
#define NMS_THR 0.7f
#define TOPN 1000

// ---------------------------------------------------------------------------
// Rotated-rect intersection area. Faithful fp32 port of the reference
// Sutherland-Hodgman clip (crossing-before-current emission, denom clamped to
// +EPS, CAP=8 truncation, shoelace with abs). ALL indices compile-time:
// appends are unrolled (s==m) selects, prev tracked incrementally -> zero
// scratch (rule #20), fully branchless -> no divergence among clip threads.
// ---------------------------------------------------------------------------
__device__ __forceinline__ float rect_inter_area(
    float xc1, float yc1, float w1, float h1, float t1,
    float xc2, float yc2, float w2, float h2, float t2)
{
    float px[CAP], py[CAP];
    {
        float c = cosf(t1), s = sinf(t1);
        float lx0 = -0.5f * w1, lx1 = 0.5f * w1;
        float ly0 = -0.5f * h1, ly1 = 0.5f * h1;
        px[0] = xc1 + lx0 * c - ly0 * s;  py[0] = yc1 + lx0 * s + ly0 * c;
        px[1] = xc1 + lx1 * c - ly0 * s;  py[1] = yc1 + lx1 * s + ly0 * c;
        px[2] = xc1 + lx1 * c - ly1 * s;  py[2] = yc1 + lx1 * s + ly1 * c;
        px[3] = xc1 + lx0 * c - ly1 * s;  py[3] = yc1 + lx0 * s + ly1 * c;
#pragma unroll
        for (int s2 = 4; s2 < CAP; ++s2) { px[s2] = 0.f; py[s2] = 0.f; }
    }
    float qx[4], qy[4];
    {
        float c = cosf(t2), s = sinf(t2);
        float lx0 = -0.5f * w2, lx1 = 0.5f * w2;
        float ly0 = -0.5f * h2, ly1 = 0.5f * h2;
        qx[0] = xc2 + lx0 * c - ly0 * s;  qy[0] = yc2 + lx0 * s + ly0 * c;
        qx[1] = xc2 + lx1 * c - ly0 * s;  qy[1] = yc2 + lx1 * s + ly0 * c;
        qx[2] = xc2 + lx1 * c - ly1 * s;  qy[2] = yc2 + lx1 * s + ly1 * c;
        qx[3] = xc2 + lx0 * c - ly1 * s;  qy[3] = yc2 + lx0 * s + ly1 * c;
    }

    int n = 4;
#pragma unroll
    for (int e = 0; e < 4; ++e) {
        float p0x = qx[e], p0y = qy[e];
        float ex = qx[(e + 1) & 3] - p0x, ey = qy[(e + 1) & 3] - p0y;

        // prev = poly[n-1] via unrolled select (compile-time indices only)
        float pxp = px[0], pyp = py[0];
#pragma unroll
        for (int s = 1; s < CAP; ++s)
            if (s == n - 1) { pxp = px[s]; pyp = py[s]; }
        float dp = ex * (pyp - p0y) - ey * (pxp - p0x);

        float nx_[CAP], ny_[CAP];
#pragma unroll
        for (int s = 0; s < CAP; ++s) { nx_[s] = 0.f; ny_[s] = 0.f; }
        int m = 0;

#pragma unroll
        for (int k = 0; k < CAP; ++k) {
            bool act = (k < n);
            float pxc = px[k], pyc = py[k];
            float dc = ex * (pyc - p0y) - ey * (pxc - p0x);
            bool cin = (dc >= 0.0f), pin = (dp >= 0.0f);

            float den = dp - dc;
            den = (fabsf(den) < EPSF) ? EPSF : den;
            float t = dp / den;
            float ix = pxp + t * (pxc - pxp);
            float iy = pyp + t * (pyc - pyp);

            bool emit_cross = act && (cin != pin);
            if (emit_cross) {
#pragma unroll
                for (int s = 0; s < CAP; ++s)
                    if (s == m) { nx_[s] = ix; ny_[s] = iy; }
                ++m;
            }
            bool emit_cur = act && cin;
            if (emit_cur) {
#pragma unroll
                for (int s = 0; s < CAP; ++s)
                    if (s == m) { nx_[s] = pxc; ny_[s] = pyc; }
                ++m;
            }
            if (act) { pxp = pxc; pyp = pyc; dp = dc; }
        }
        n = (m < CAP) ? m : CAP;
#pragma unroll
        for (int s = 0; s < CAP; ++s) { px[s] = nx_[s]; py[s] = ny_[s]; }
    }

    if (n < 3) return 0.0f;
    float s = 0.0f;
#pragma unroll
    for (int k = 0; k < CAP; ++k) {
        if (k < n) {
            float nxk = px[(k + 1) & (CAP - 1)];
            float nyk = py[(k + 1) & (CAP - 1)];
            if (k == n - 1) { nxk = px[0]; nyk = py[0]; }
            s += px[k] * nyk - py[k] * nxk;
        }
    }
    return 0.5f * fabsf(s);
}

// ---------------------------------------------------------------------------
// Phase A: cheap conservative rejects; survivors appended to a compact pair
// list. On list overflow (tiny ws), clip inline (correct for any ws_size).
// ---------------------------------------------------------------------------
__global__ __launch_bounds__(256)
void filter_kernel(const float* __restrict__ boxes,
                   unsigned long long* __restrict__ mask,
                   unsigned int* counter, unsigned int* pairs,
                   unsigned int pairs_cap, int n, int words)
{
    int i = blockIdx.y;
    int jbase = blockIdx.x * 256;
    if (jbase + 255 <= i) return;                 // block fully below diagonal
    int j = jbase + threadIdx.x;
    if (j >= n || j <= i) return;

    const float* bi = boxes + (size_t)i * 5;
    const float* bj = boxes + (size_t)j * 5;
    float xi = bi[0], yi = bi[1], wi = bi[2], hi = bi[3];
    float xj = bj[0], yj = bj[1], wj = bj[2], hj = bj[3];

    float dx = xi - xj, dy = yi - yj;
    float ri = 0.5f * sqrtf(wi * wi + hi * hi);
    float rj = 0.5f * sqrtf(wj * wj + hj * hj);
    float rr = ri + rj + 1e-2f;
    if (dx * dx + dy * dy > rr * rr) return;      // disjoint -> inter == 0

    float a1 = wi * hi, a2 = wj * hj;
    float amin = fminf(a1, a2), amax = fmaxf(a1, a2);
    if (amin < 0.699f * amax) return;             // iou bound < threshold

    if (counter) {
        unsigned int idx = atomicAdd(counter, 1u);
        if (idx < pairs_cap) {
            pairs[idx] = ((unsigned int)i << 16) | (unsigned int)j;
            return;
        }
    }
    // overflow / no-list fallback: clip inline
    float inter = rect_inter_area(xi, yi, wi, hi, bi[4], xj, yj, wj, hj, bj[4]);
    float iou = inter / (a1 + a2 - inter + EPSF);
    if (iou >= NMS_THR)
        atomicOr(&mask[(size_t)i * words + (j >> 6)], 1ULL << (j & 63));
}

// ---------------------------------------------------------------------------
// Phase B: full clip on the compacted survivor list (every lane busy).
// ---------------------------------------------------------------------------
__global__ __launch_bounds__(256)
void clip_kernel(const float* __restrict__ boxes,
                 const unsigned int* __restrict__ counter,
                 const unsigned int* __restrict__ pairs,
                 unsigned int pairs_cap,
                 unsigned long long* __restrict__ mask, int words)
{
    unsigned int cnt = counter[0];
    if (cnt > pairs_cap) cnt = pairs_cap;
    for (unsigned int p = blockIdx.x * blockDim.x + threadIdx.x; p < cnt;
         p += gridDim.x * blockDim.x) {
        unsigned int pk = pairs[p];
        int i = (int)(pk >> 16), j = (int)(pk & 0xffffu);
        const float* bi = boxes + (size_t)i * 5;
        const float* bj = boxes + (size_t)j * 5;
        float wi = bi[2], hi = bi[3], wj = bj[2], hj = bj[3];
        float a1 = wi * hi, a2 = wj * hj;
        float inter = rect_inter_area(bi[0], bi[1], wi, hi, bi[4],
                                      bj[0], bj[1], wj, hj, bj[4]);
        float iou = inter / (a1 + a2 - inter + EPSF);
        if (iou >= NMS_THR)
            atomicOr(&mask[(size_t)i * words + (j >> 6)], 1ULL << (j & 63));
    }
}

// ---------------------------------------------------------------------------
// Greedy NMS, one wave. Lanes 0..31 own one 64-bit word of the running
// suppressed mask. Per 64-box chunk the chunk word cw is pulled ONCE via
// v_readlane (uniform scalar chain; no per-box ds_bpermute). cw only needs a
// readlane update when a kept box actually suppresses someone (rare: __any).
// Rows prefetched through two 32-deep static register rings.
// ---------------------------------------------------------------------------
__global__ __launch_bounds__(64)
void greedy_kernel(const unsigned long long* __restrict__ mask,
                   int* __restrict__ keep, int n, int words)
{
    const int lane = threadIdx.x;
    const bool owner = (lane < words);
    unsigned long long sup = 0ULL;
    unsigned long long bufA[32], bufB[32];
    int cnt = 0;

    auto loadrow = [&](int r) -> unsigned long long {
        int rc = (r < n) ? r : (n - 1);
        return owner ? mask[(size_t)rc * words + lane] : 0ULL;
    };

#pragma unroll
    for (int k = 0; k < 32; ++k) bufA[k] = loadrow(k);
#pragma unroll
    for (int k = 0; k < 32; ++k) bufB[k] = loadrow(32 + k);

    const int chunks = (n + 63) >> 6;
    for (int c = 0; c < chunks; ++c) {
        if (cnt >= TOPN) break;
        unsigned int cwlo = (unsigned int)__builtin_amdgcn_readlane((int)(unsigned int)sup, c);
        unsigned int cwhi = (unsigned int)__builtin_amdgcn_readlane((int)(unsigned int)(sup >> 32), c);
        unsigned long long cw = ((unsigned long long)cwhi << 32) | cwlo;

        // ---- half 0: boxes 64c .. 64c+31 (bufA) ----
#pragma unroll
        for (int k = 0; k < 32; ++k) {
            int i = (c << 6) + k;
            bool bit = (cw >> k) & 1ULL;
            if (!bit && cnt < TOPN && i < n) {
                keep[cnt] = i;            // wave-uniform store, one request
                ++cnt;
                unsigned long long rowv = bufA[k];
                if (__any(rowv != 0ULL)) {
                    sup |= rowv;
                    unsigned int rl = (unsigned int)__builtin_amdgcn_readlane((int)(unsigned int)rowv, c);
                    unsigned int rh = (unsigned int)__builtin_amdgcn_readlane((int)(unsigned int)(rowv >> 32), c);
                    cw |= ((unsigned long long)rh << 32) | rl;
                }
            }
        }
        // refill bufA with chunk c+1, half 0
#pragma unroll
        for (int k = 0; k < 32; ++k) bufA[k] = loadrow(((c + 1) << 6) + k);

        // ---- half 1: boxes 64c+32 .. 64c+63 (bufB) ----
#pragma unroll
        for (int k = 0; k < 32; ++k) {
            int i = (c << 6) + 32 + k;
            bool bit = (cw >> (32 + k)) & 1ULL;
            if (!bit && cnt < TOPN && i < n) {
                keep[cnt] = i;
                ++cnt;
                unsigned long long rowv = bufB[k];
                if (__any(rowv != 0ULL)) {
                    sup |= rowv;
                    unsigned int rl = (unsigned int)__builtin_amdgcn_readlane((int)(unsigned int)rowv, c);
                    unsigned int rh = (unsigned int)__builtin_amdgcn_readlane((int)(unsigned int)(rowv >> 32), c);
                    cw |= ((unsigned long long)rh << 32) | rl;
                }
            }
        }
        // refill bufB with chunk c+1, half 1
#pragma unroll
        for (int k = 0; k < 32; ++k) bufB[k] = loadrow(((c + 1) << 6) + 32 + k);
    }
}

extern "C" void kernel_launch(void* const* d_in, const int* in_sizes, int n_in,
                              void* d_out, int out_size, void* d_ws, size_t ws_size,
                              hipStream_t stream) {
    const float* boxes = (const float*)d_in[0];
    int n = in_sizes[0] / 5;                    // 2048
    int words = (n + 63) / 64;                  // 32
    int* keep = (int*)d_out;
    unsigned long long* mask = (unsigned long long*)d_ws;
    size_t mask_bytes = (size_t)n * words * sizeof(unsigned long long);

    bool have_list = ws_size >= mask_bytes + 4096;
    unsigned int* counter = have_list
        ? (unsigned int*)((char*)d_ws + mask_bytes) : nullptr;
    unsigned int* pairs = have_list ? counter + 4 : nullptr;  // +16 bytes
    unsigned int pairs_cap = have_list
        ? (unsigned int)((ws_size - mask_bytes - 16) / 4) : 0u;

    hipMemsetAsync(mask, 0, mask_bytes + (have_list ? 16 : 0), stream);
    hipMemsetAsync(d_out, 0xFF, (size_t)out_size * sizeof(int), stream);

    dim3 grid((n + 255) / 256, n);
    filter_kernel<<<grid, 256, 0, stream>>>(boxes, mask, counter, pairs,
                                            pairs_cap, n, words);
    if (have_list)
        clip_kernel<<<128, 256, 0, stream>>>(boxes, counter, pairs, pairs_cap,
                                             mask, words);
    greedy_kernel<<<1, 64, 0, stream>>>(mask, keep, n, words);
}

// Round 3
// 176.818 us; speedup vs baseline: 1.5343x; 1.5343x over previous
//
#include <hip/hip_runtime.h>
#include <hip/hip_bf16.h>

#define CAP 8
#define EPSF 1e-8f
#define NMS_THR 0.7f
#define TOPN 1000

// ---------------------------------------------------------------------------
// Rotated-rect intersection area. Faithful fp32 port of the reference
// Sutherland-Hodgman clip (crossing-before-current emission, denom clamped to
// +EPS, CAP=8 truncation, shoelace with abs). ALL indices compile-time:
// appends are unrolled (s==m) selects, prev tracked incrementally -> zero
// scratch (rule #20), fully branchless. Verified absmax==0 in R1/R2.
// ---------------------------------------------------------------------------
__device__ __forceinline__ float rect_inter_area(
    float xc1, float yc1, float w1, float h1, float t1,
    float xc2, float yc2, float w2, float h2, float t2)
{
    float px[CAP], py[CAP];
    {
        float c = cosf(t1), s = sinf(t1);
        float lx0 = -0.5f * w1, lx1 = 0.5f * w1;
        float ly0 = -0.5f * h1, ly1 = 0.5f * h1;
        px[0] = xc1 + lx0 * c - ly0 * s;  py[0] = yc1 + lx0 * s + ly0 * c;
        px[1] = xc1 + lx1 * c - ly0 * s;  py[1] = yc1 + lx1 * s + ly0 * c;
        px[2] = xc1 + lx1 * c - ly1 * s;  py[2] = yc1 + lx1 * s + ly1 * c;
        px[3] = xc1 + lx0 * c - ly1 * s;  py[3] = yc1 + lx0 * s + ly1 * c;
#pragma unroll
        for (int s2 = 4; s2 < CAP; ++s2) { px[s2] = 0.f; py[s2] = 0.f; }
    }
    float qx[4], qy[4];
    {
        float c = cosf(t2), s = sinf(t2);
        float lx0 = -0.5f * w2, lx1 = 0.5f * w2;
        float ly0 = -0.5f * h2, ly1 = 0.5f * h2;
        qx[0] = xc2 + lx0 * c - ly0 * s;  qy[0] = yc2 + lx0 * s + ly0 * c;
        qx[1] = xc2 + lx1 * c - ly0 * s;  qy[1] = yc2 + lx1 * s + ly0 * c;
        qx[2] = xc2 + lx1 * c - ly1 * s;  qy[2] = yc2 + lx1 * s + ly1 * c;
        qx[3] = xc2 + lx0 * c - ly1 * s;  qy[3] = yc2 + lx0 * s + ly1 * c;
    }

    int n = 4;
#pragma unroll
    for (int e = 0; e < 4; ++e) {
        float p0x = qx[e], p0y = qy[e];
        float ex = qx[(e + 1) & 3] - p0x, ey = qy[(e + 1) & 3] - p0y;

        // prev = poly[n-1] via unrolled select (compile-time indices only)
        float pxp = px[0], pyp = py[0];
#pragma unroll
        for (int s = 1; s < CAP; ++s)
            if (s == n - 1) { pxp = px[s]; pyp = py[s]; }
        float dp = ex * (pyp - p0y) - ey * (pxp - p0x);

        float nx_[CAP], ny_[CAP];
#pragma unroll
        for (int s = 0; s < CAP; ++s) { nx_[s] = 0.f; ny_[s] = 0.f; }
        int m = 0;

#pragma unroll
        for (int k = 0; k < CAP; ++k) {
            bool act = (k < n);
            float pxc = px[k], pyc = py[k];
            float dc = ex * (pyc - p0y) - ey * (pxc - p0x);
            bool cin = (dc >= 0.0f), pin = (dp >= 0.0f);

            float den = dp - dc;
            den = (fabsf(den) < EPSF) ? EPSF : den;
            float t = dp / den;
            float ix = pxp + t * (pxc - pxp);
            float iy = pyp + t * (pyc - pyp);

            bool emit_cross = act && (cin != pin);
            if (emit_cross) {
#pragma unroll
                for (int s = 0; s < CAP; ++s)
                    if (s == m) { nx_[s] = ix; ny_[s] = iy; }
                ++m;
            }
            bool emit_cur = act && cin;
            if (emit_cur) {
#pragma unroll
                for (int s = 0; s < CAP; ++s)
                    if (s == m) { nx_[s] = pxc; ny_[s] = pyc; }
                ++m;
            }
            if (act) { pxp = pxc; pyp = pyc; dp = dc; }
        }
        n = (m < CAP) ? m : CAP;
#pragma unroll
        for (int s = 0; s < CAP; ++s) { px[s] = nx_[s]; py[s] = ny_[s]; }
    }

    if (n < 3) return 0.0f;
    float s = 0.0f;
#pragma unroll
    for (int k = 0; k < CAP; ++k) {
        if (k < n) {
            float nxk = px[(k + 1) & (CAP - 1)];
            float nyk = py[(k + 1) & (CAP - 1)];
            if (k == n - 1) { nxk = px[0]; nyk = py[0]; }
            s += px[k] * nyk - py[k] * nxk;
        }
    }
    return 0.5f * fabsf(s);
}

// ---------------------------------------------------------------------------
// Pair kernel: cheap conservative rejects, then INLINE branchless clip for
// the ~1.5% survivors (zero scratch -> ~1000 cy register math, hidden by
// TLP). No compaction list, no contended atomics: only rare atomicOr to
// 64K distinct mask words.
// ---------------------------------------------------------------------------
__global__ __launch_bounds__(256)
void filter_kernel(const float* __restrict__ boxes,
                   unsigned long long* __restrict__ mask,
                   int n, int words)
{
    int i = blockIdx.y;
    int jbase = blockIdx.x * 256;
    if (jbase + 255 <= i) return;                 // block fully at/below diag
    int j = jbase + threadIdx.x;
    if (j >= n || j <= i) return;

    const float* bi = boxes + (size_t)i * 5;
    const float* bj = boxes + (size_t)j * 5;
    float xi = bi[0], yi = bi[1], wi = bi[2], hi = bi[3];
    float xj = bj[0], yj = bj[1], wj = bj[2], hj = bj[3];

    // Bounding-circle reject: disjoint => inter exactly 0 in the reference.
    float dx = xi - xj, dy = yi - yj;
    float ri = 0.5f * sqrtf(wi * wi + hi * hi);
    float rj = 0.5f * sqrtf(wj * wj + hj * hj);
    float rr = ri + rj + 1e-2f;
    if (dx * dx + dy * dy > rr * rr) return;

    // Area-ratio reject: max possible iou = amin/amax (margin for fp noise).
    float a1 = wi * hi, a2 = wj * hj;
    float amin = fminf(a1, a2), amax = fmaxf(a1, a2);
    if (amin < 0.699f * amax) return;

    float inter = rect_inter_area(xi, yi, wi, hi, bi[4], xj, yj, wj, hj, bj[4]);
    float iou = inter / (a1 + a2 - inter + EPSF);
    if (iou >= NMS_THR)
        atomicOr(&mask[(size_t)i * words + (j >> 6)], 1ULL << (j & 63));
}

// ---------------------------------------------------------------------------
// Greedy NMS, one wave. Lanes 0..31 own one 64-bit word of the running
// suppressed mask. Per 64-box chunk the chunk word cw is pulled ONCE via
// v_readlane (uniform scalar chain; no per-box ds_bpermute). cw only needs a
// readlane update when a kept box actually suppresses someone (rare: __any).
// Rows prefetched through two 32-deep static register rings.
// ---------------------------------------------------------------------------
__global__ __launch_bounds__(64)
void greedy_kernel(const unsigned long long* __restrict__ mask,
                   int* __restrict__ keep, int n, int words)
{
    const int lane = threadIdx.x;
    const bool owner = (lane < words);
    unsigned long long sup = 0ULL;
    unsigned long long bufA[32], bufB[32];
    int cnt = 0;

    auto loadrow = [&](int r) -> unsigned long long {
        int rc = (r < n) ? r : (n - 1);
        return owner ? mask[(size_t)rc * words + lane] : 0ULL;
    };

#pragma unroll
    for (int k = 0; k < 32; ++k) bufA[k] = loadrow(k);
#pragma unroll
    for (int k = 0; k < 32; ++k) bufB[k] = loadrow(32 + k);

    const int chunks = (n + 63) >> 6;
    for (int c = 0; c < chunks; ++c) {
        if (cnt >= TOPN) break;
        unsigned int cwlo = (unsigned int)__builtin_amdgcn_readlane((int)(unsigned int)sup, c);
        unsigned int cwhi = (unsigned int)__builtin_amdgcn_readlane((int)(unsigned int)(sup >> 32), c);
        unsigned long long cw = ((unsigned long long)cwhi << 32) | cwlo;

        // ---- half 0: boxes 64c .. 64c+31 (bufA) ----
#pragma unroll
        for (int k = 0; k < 32; ++k) {
            int i = (c << 6) + k;
            bool bit = (cw >> k) & 1ULL;
            if (!bit && cnt < TOPN && i < n) {
                keep[cnt] = i;            // wave-uniform store, one request
                ++cnt;
                unsigned long long rowv = bufA[k];
                if (__any(rowv != 0ULL)) {
                    sup |= rowv;
                    unsigned int rl = (unsigned int)__builtin_amdgcn_readlane((int)(unsigned int)rowv, c);
                    unsigned int rh = (unsigned int)__builtin_amdgcn_readlane((int)(unsigned int)(rowv >> 32), c);
                    cw |= ((unsigned long long)rh << 32) | rl;
                }
            }
        }
        // refill bufA with chunk c+1, half 0
#pragma unroll
        for (int k = 0; k < 32; ++k) bufA[k] = loadrow(((c + 1) << 6) + k);

        // ---- half 1: boxes 64c+32 .. 64c+63 (bufB) ----
#pragma unroll
        for (int k = 0; k < 32; ++k) {
            int i = (c << 6) + 32 + k;
            bool bit = (cw >> (32 + k)) & 1ULL;
            if (!bit && cnt < TOPN && i < n) {
                keep[cnt] = i;
                ++cnt;
                unsigned long long rowv = bufB[k];
                if (__any(rowv != 0ULL)) {
                    sup |= rowv;
                    unsigned int rl = (unsigned int)__builtin_amdgcn_readlane((int)(unsigned int)rowv, c);
                    unsigned int rh = (unsigned int)__builtin_amdgcn_readlane((int)(unsigned int)(rowv >> 32), c);
                    cw |= ((unsigned long long)rh << 32) | rl;
                }
            }
        }
        // refill bufB with chunk c+1, half 1
#pragma unroll
        for (int k = 0; k < 32; ++k) bufB[k] = loadrow(((c + 1) << 6) + 32 + k);
    }
}

extern "C" void kernel_launch(void* const* d_in, const int* in_sizes, int n_in,
                              void* d_out, int out_size, void* d_ws, size_t ws_size,
                              hipStream_t stream) {
    const float* boxes = (const float*)d_in[0];
    int n = in_sizes[0] / 5;                    // 2048
    int words = (n + 63) / 64;                  // 32
    int* keep = (int*)d_out;
    unsigned long long* mask = (unsigned long long*)d_ws;
    size_t mask_bytes = (size_t)n * words * sizeof(unsigned long long);

    hipMemsetAsync(mask, 0, mask_bytes, stream);
    hipMemsetAsync(d_out, 0xFF, (size_t)out_size * sizeof(int), stream);

    dim3 grid((n + 255) / 256, n);
    filter_kernel<<<grid, 256, 0, stream>>>(boxes, mask, n, words);
    greedy_kernel<<<1, 64, 0, stream>>>(mask, keep, n, words);
}

// Round 4
// 169.894 us; speedup vs baseline: 1.5968x; 1.0408x over previous
//
#include <hip/hip_runtime.h>
#include <hip/hip_bf16.h>

#define CAP 8
#define EPSF 1e-8f
#define NMS_THR 0.7f
#define TOPN 1000

#define GLOBAL_AS __attribute__((address_space(1)))
#define LDS_AS    __attribute__((address_space(3)))

// ---------------------------------------------------------------------------
// Rotated-rect intersection area. Faithful fp32 port of the reference
// Sutherland-Hodgman clip (crossing-before-current emission, denom clamped to
// +EPS, CAP=8 truncation, shoelace with abs). ALL indices compile-time ->
// zero scratch, fully branchless. Verified absmax==0 in R1-R3.
// ---------------------------------------------------------------------------
__device__ __forceinline__ float rect_inter_area(
    float xc1, float yc1, float w1, float h1, float t1,
    float xc2, float yc2, float w2, float h2, float t2)
{
    float px[CAP], py[CAP];
    {
        float c = cosf(t1), s = sinf(t1);
        float lx0 = -0.5f * w1, lx1 = 0.5f * w1;
        float ly0 = -0.5f * h1, ly1 = 0.5f * h1;
        px[0] = xc1 + lx0 * c - ly0 * s;  py[0] = yc1 + lx0 * s + ly0 * c;
        px[1] = xc1 + lx1 * c - ly0 * s;  py[1] = yc1 + lx1 * s + ly0 * c;
        px[2] = xc1 + lx1 * c - ly1 * s;  py[2] = yc1 + lx1 * s + ly1 * c;
        px[3] = xc1 + lx0 * c - ly1 * s;  py[3] = yc1 + lx0 * s + ly1 * c;
#pragma unroll
        for (int s2 = 4; s2 < CAP; ++s2) { px[s2] = 0.f; py[s2] = 0.f; }
    }
    float qx[4], qy[4];
    {
        float c = cosf(t2), s = sinf(t2);
        float lx0 = -0.5f * w2, lx1 = 0.5f * w2;
        float ly0 = -0.5f * h2, ly1 = 0.5f * h2;
        qx[0] = xc2 + lx0 * c - ly0 * s;  qy[0] = yc2 + lx0 * s + ly0 * c;
        qx[1] = xc2 + lx1 * c - ly0 * s;  qy[1] = yc2 + lx1 * s + ly0 * c;
        qx[2] = xc2 + lx1 * c - ly1 * s;  qy[2] = yc2 + lx1 * s + ly1 * c;
        qx[3] = xc2 + lx0 * c - ly1 * s;  qy[3] = yc2 + lx0 * s + ly1 * c;
    }

    int n = 4;
#pragma unroll
    for (int e = 0; e < 4; ++e) {
        float p0x = qx[e], p0y = qy[e];
        float ex = qx[(e + 1) & 3] - p0x, ey = qy[(e + 1) & 3] - p0y;

        float pxp = px[0], pyp = py[0];
#pragma unroll
        for (int s = 1; s < CAP; ++s)
            if (s == n - 1) { pxp = px[s]; pyp = py[s]; }
        float dp = ex * (pyp - p0y) - ey * (pxp - p0x);

        float nx_[CAP], ny_[CAP];
#pragma unroll
        for (int s = 0; s < CAP; ++s) { nx_[s] = 0.f; ny_[s] = 0.f; }
        int m = 0;

#pragma unroll
        for (int k = 0; k < CAP; ++k) {
            bool act = (k < n);
            float pxc = px[k], pyc = py[k];
            float dc = ex * (pyc - p0y) - ey * (pxc - p0x);
            bool cin = (dc >= 0.0f), pin = (dp >= 0.0f);

            float den = dp - dc;
            den = (fabsf(den) < EPSF) ? EPSF : den;
            float t = dp / den;
            float ix = pxp + t * (pxc - pxp);
            float iy = pyp + t * (pyc - pyp);

            bool emit_cross = act && (cin != pin);
            if (emit_cross) {
#pragma unroll
                for (int s = 0; s < CAP; ++s)
                    if (s == m) { nx_[s] = ix; ny_[s] = iy; }
                ++m;
            }
            bool emit_cur = act && cin;
            if (emit_cur) {
#pragma unroll
                for (int s = 0; s < CAP; ++s)
                    if (s == m) { nx_[s] = pxc; ny_[s] = pyc; }
                ++m;
            }
            if (act) { pxp = pxc; pyp = pyc; dp = dc; }
        }
        n = (m < CAP) ? m : CAP;
#pragma unroll
        for (int s = 0; s < CAP; ++s) { px[s] = nx_[s]; py[s] = ny_[s]; }
    }

    if (n < 3) return 0.0f;
    float s = 0.0f;
#pragma unroll
    for (int k = 0; k < CAP; ++k) {
        if (k < n) {
            float nxk = px[(k + 1) & (CAP - 1)];
            float nyk = py[(k + 1) & (CAP - 1)];
            if (k == n - 1) { nxk = px[0]; nyk = py[0]; }
            s += px[k] * nyk - py[k] * nxk;
        }
    }
    return 0.5f * fabsf(s);
}

// ---------------------------------------------------------------------------
// Pair kernel: cheap conservative rejects, then inline branchless clip for
// ~1.5% survivors. Word index XOR-swizzled by (i&swz) so greedy's LDS reads
// are bank-conflict-free (swizzle applied write-side here, read-side there).
// ---------------------------------------------------------------------------
__global__ __launch_bounds__(256)
void filter_kernel(const float* __restrict__ boxes,
                   unsigned long long* __restrict__ mask,
                   int n, int words, int swz)
{
    int i = blockIdx.y;
    int jbase = blockIdx.x * 256;
    if (jbase + 255 <= i) return;
    int j = jbase + threadIdx.x;
    if (j >= n || j <= i) return;

    const float* bi = boxes + (size_t)i * 5;
    const float* bj = boxes + (size_t)j * 5;
    float xi = bi[0], yi = bi[1], wi = bi[2], hi = bi[3];
    float xj = bj[0], yj = bj[1], wj = bj[2], hj = bj[3];

    float dx = xi - xj, dy = yi - yj;
    float ri = 0.5f * sqrtf(wi * wi + hi * hi);
    float rj = 0.5f * sqrtf(wj * wj + hj * hj);
    float rr = ri + rj + 1e-2f;
    if (dx * dx + dy * dy > rr * rr) return;

    float a1 = wi * hi, a2 = wj * hj;
    float amin = fminf(a1, a2), amax = fmaxf(a1, a2);
    if (amin < 0.699f * amax) return;

    float inter = rect_inter_area(xi, yi, wi, hi, bi[4], xj, yj, wj, hj, bj[4]);
    float iou = inter / (a1 + a2 - inter + EPSF);
    if (iou >= NMS_THR) {
        int slot = (j >> 6) ^ (i & swz);
        atomicOr(&mask[(size_t)i * words + slot], 1ULL << (j & 63));
    }
}

__device__ __forceinline__ unsigned long long rl64(unsigned long long v, int l) {
    unsigned int lo = (unsigned int)__builtin_amdgcn_readlane((int)(unsigned int)v, l);
    unsigned int hi = (unsigned int)__builtin_amdgcn_readlane((int)(v >> 32), l);
    return ((unsigned long long)hi << 32) | lo;
}

// ---------------------------------------------------------------------------
// Greedy NMS, one wave. Serial core uses ONLY the chunk-diagonal words
// (1 u64/lane, lane k holds row base+k's word c) -> ~12 VGPRs, no spill.
// Rows streamed chunk-ahead into a 32KB LDS double buffer via
// global_load_lds (uniform LDS base + lane*16 global src, linear layout).
// Kept rows OR'd into distributed acc (lane w owns word w; two lane-groups
// split rows) in 16-deep ds_read batches. One vmcnt(0) per chunk, a full
// chunk after issue.
// ---------------------------------------------------------------------------
__global__ __launch_bounds__(64, 1)
void greedy_kernel(const unsigned long long* __restrict__ mask,
                   int* __restrict__ keep, int n, int words, int swz)
{
    __shared__ unsigned long long lds[2 * 2048];   // 2 bufs x 64 rows x <=32 words
    const int lane = threadIdx.x;
    const int g = lane >> 5;          // lane group for OR-step row split
    const int w = lane & 31;          // word owned by this lane
    const int chunks = (n + 63) >> 6;

    // ---- prefetch chunk 0 into buf 0 ----
    {
        const char* src = (const char*)mask + (size_t)lane * 16;
        char* dst = (char*)&lds[0];
        for (int t = 0; t < (words >> 1); ++t)
            __builtin_amdgcn_global_load_lds(
                (const GLOBAL_AS unsigned int*)(src + t * 1024),
                (LDS_AS unsigned int*)(dst + t * 1024), 16, 0, 0);
    }
    asm volatile("s_waitcnt vmcnt(0)" ::: "memory");

    unsigned long long acc = 0ULL;    // OR of kept rows' word w (per group g)
    int cnt = 0;

    for (int c = 0; c < chunks; ++c) {
        if (cnt >= TOPN) break;
        const int b = c & 1;
        const int base = c << 6;

        // issue prefetch of chunk c+1 into the other buffer (no wait)
        if (c + 1 < chunks) {
            const char* src = (const char*)mask +
                (size_t)(c + 1) * 64 * words * 8 + (size_t)lane * 16;
            char* dst = (char*)&lds[(size_t)(b ^ 1) * 2048];
            for (int t = 0; t < (words >> 1); ++t)
                __builtin_amdgcn_global_load_lds(
                    (const GLOBAL_AS unsigned int*)(src + t * 1024),
                    (LDS_AS unsigned int*)(dst + t * 1024), 16, 0, 0);
        }

        // current suppression word for this chunk (both groups)
        unsigned long long cw = rl64(acc, c) | rl64(acc, 32 + c);

        // diagonal: lane k holds row (base+k)'s word c (swizzled slot)
        unsigned long long D =
            lds[(size_t)b * 2048 + (size_t)lane * words + (c ^ (lane & swz))];

        // ---- serial scan over the 64 boxes of this chunk ----
        unsigned long long kmask = 0ULL;
#pragma unroll
        for (int k = 0; k < 64; ++k) {
            if (!((cw >> k) & 1ULL) && cnt < TOPN && (base + k) < n) {
                keep[cnt] = base + k;     // same addr+data on all lanes: ok
                ++cnt;
                cw |= rl64(D, k);         // literal lane index (unrolled)
                kmask |= (1ULL << k);
            }
        }

        // ---- OR kept rows into distributed acc (group-split, batched) ----
        unsigned long long km = kmask;
        int parity = 0;
        while (km) {
#pragma unroll
            for (int t = 0; t < 16; ++t) {
                unsigned long long rv = 0ULL;
                if (km) {
                    int r = (int)__builtin_ctzll(km);
                    km &= km - 1;
                    if (g == parity)
                        rv = lds[(size_t)b * 2048 + (size_t)r * words +
                                 (w ^ (r & swz))];
                    parity ^= 1;
                }
                acc |= rv;
            }
        }

        // chunk c+1 data must be resident before next iteration
        asm volatile("s_waitcnt vmcnt(0)" ::: "memory");
    }

    // tail fill: keep[cnt..TOPN-1] = -1 (replaces d_out memset)
    for (int t = cnt + lane; t < TOPN; t += 64) keep[t] = -1;
}

extern "C" void kernel_launch(void* const* d_in, const int* in_sizes, int n_in,
                              void* d_out, int out_size, void* d_ws, size_t ws_size,
                              hipStream_t stream) {
    const float* boxes = (const float*)d_in[0];
    int n = in_sizes[0] / 5;                    // 2048
    int words = (n + 63) / 64;                  // 32
    int swz = (words == 32) ? 31 : 0;           // swizzle only in the even case
    int* keep = (int*)d_out;
    unsigned long long* mask = (unsigned long long*)d_ws;
    size_t mask_bytes = (size_t)n * words * sizeof(unsigned long long);

    hipMemsetAsync(mask, 0, mask_bytes, stream);

    dim3 grid((n + 255) / 256, n);
    filter_kernel<<<grid, 256, 0, stream>>>(boxes, mask, n, words, swz);
    greedy_kernel<<<1, 64, 0, stream>>>(mask, keep, n, words, swz);
}

// Round 5
// 64.594 us; speedup vs baseline: 4.1999x; 2.6302x over previous
//
#include <hip/hip_runtime.h>
#include <hip/hip_bf16.h>

#define CAP 8
#define EPSF 1e-8f
#define NMS_THR 0.7f
#define TOPN 1000

#define GLOBAL_AS __attribute__((address_space(1)))
#define LDS_AS    __attribute__((address_space(3)))

// ---------------------------------------------------------------------------
// Rotated-rect intersection area from center/size/cos/sin. Faithful fp32 port
// of the reference Sutherland-Hodgman clip (crossing-before-current emission,
// denom clamped to +EPS, CAP=8 truncation, shoelace with abs). ALL indices
// compile-time -> zero scratch, fully branchless. Verified absmax==0 R1-R4.
// ---------------------------------------------------------------------------
__device__ __forceinline__ float rect_inter_area_cs(
    float xc1, float yc1, float w1, float h1, float c1, float s1,
    float xc2, float yc2, float w2, float h2, float c2, float s2)
{
    float px[CAP], py[CAP];
    {
        float lx0 = -0.5f * w1, lx1 = 0.5f * w1;
        float ly0 = -0.5f * h1, ly1 = 0.5f * h1;
        px[0] = xc1 + lx0 * c1 - ly0 * s1;  py[0] = yc1 + lx0 * s1 + ly0 * c1;
        px[1] = xc1 + lx1 * c1 - ly0 * s1;  py[1] = yc1 + lx1 * s1 + ly0 * c1;
        px[2] = xc1 + lx1 * c1 - ly1 * s1;  py[2] = yc1 + lx1 * s1 + ly1 * c1;
        px[3] = xc1 + lx0 * c1 - ly1 * s1;  py[3] = yc1 + lx0 * s1 + ly1 * c1;
#pragma unroll
        for (int s2i = 4; s2i < CAP; ++s2i) { px[s2i] = 0.f; py[s2i] = 0.f; }
    }
    float qx[4], qy[4];
    {
        float lx0 = -0.5f * w2, lx1 = 0.5f * w2;
        float ly0 = -0.5f * h2, ly1 = 0.5f * h2;
        qx[0] = xc2 + lx0 * c2 - ly0 * s2;  qy[0] = yc2 + lx0 * s2 + ly0 * c2;
        qx[1] = xc2 + lx1 * c2 - ly0 * s2;  qy[1] = yc2 + lx1 * s2 + ly0 * c2;
        qx[2] = xc2 + lx1 * c2 - ly1 * s2;  qy[2] = yc2 + lx1 * s2 + ly1 * c2;
        qx[3] = xc2 + lx0 * c2 - ly1 * s2;  qy[3] = yc2 + lx0 * s2 + ly1 * c2;
    }

    int n = 4;
#pragma unroll
    for (int e = 0; e < 4; ++e) {
        float p0x = qx[e], p0y = qy[e];
        float ex = qx[(e + 1) & 3] - p0x, ey = qy[(e + 1) & 3] - p0y;

        float pxp = px[0], pyp = py[0];
#pragma unroll
        for (int s = 1; s < CAP; ++s)
            if (s == n - 1) { pxp = px[s]; pyp = py[s]; }
        float dp = ex * (pyp - p0y) - ey * (pxp - p0x);

        float nx_[CAP], ny_[CAP];
#pragma unroll
        for (int s = 0; s < CAP; ++s) { nx_[s] = 0.f; ny_[s] = 0.f; }
        int m = 0;

#pragma unroll
        for (int k = 0; k < CAP; ++k) {
            bool act = (k < n);
            float pxc = px[k], pyc = py[k];
            float dc = ex * (pyc - p0y) - ey * (pxc - p0x);
            bool cin = (dc >= 0.0f), pin = (dp >= 0.0f);

            float den = dp - dc;
            den = (fabsf(den) < EPSF) ? EPSF : den;
            float t = dp / den;
            float ix = pxp + t * (pxc - pxp);
            float iy = pyp + t * (pyc - pyp);

            bool emit_cross = act && (cin != pin);
            if (emit_cross) {
#pragma unroll
                for (int s = 0; s < CAP; ++s)
                    if (s == m) { nx_[s] = ix; ny_[s] = iy; }
                ++m;
            }
            bool emit_cur = act && cin;
            if (emit_cur) {
#pragma unroll
                for (int s = 0; s < CAP; ++s)
                    if (s == m) { nx_[s] = pxc; ny_[s] = pyc; }
                ++m;
            }
            if (act) { pxp = pxc; pyp = pyc; dp = dc; }
        }
        n = (m < CAP) ? m : CAP;
#pragma unroll
        for (int s = 0; s < CAP; ++s) { px[s] = nx_[s]; py[s] = ny_[s]; }
    }

    if (n < 3) return 0.0f;
    float s = 0.0f;
#pragma unroll
    for (int k = 0; k < CAP; ++k) {
        if (k < n) {
            float nxk = px[(k + 1) & (CAP - 1)];
            float nyk = py[(k + 1) & (CAP - 1)];
            if (k == n - 1) { nxk = px[0]; nyk = py[0]; }
            s += px[k] * nyk - py[k] * nxk;
        }
    }
    return 0.5f * fabsf(s);
}

// ---------------------------------------------------------------------------
// Prep: per-box [x,y,w,h | cos,sin, r=half-diag, area] as 2x float4 (32B).
// Removes per-pair sqrt (x2) and per-clip trig (x4) from the hot kernel.
// ---------------------------------------------------------------------------
__global__ __launch_bounds__(256)
void prep_kernel(const float* __restrict__ boxes, float4* __restrict__ box8,
                 int n)
{
    int i = blockIdx.x * 256 + threadIdx.x;
    if (i >= n) return;
    const float* b = boxes + (size_t)i * 5;
    float x = b[0], y = b[1], w = b[2], h = b[3], t = b[4];
    box8[2 * i]     = make_float4(x, y, w, h);
    box8[2 * i + 1] = make_float4(cosf(t), sinf(t),
                                  0.5f * sqrtf(w * w + h * h), w * h);
}

// ---------------------------------------------------------------------------
// Pair kernel: cheap conservative rejects, inline branchless clip for the
// ~1.5% survivors. Mask word index XOR-swizzled by (i&swz) for greedy's LDS
// bank pattern (write-side here, read-side there: both-or-neither). Also
// sets the per-row nonzero summary bit (rare atomicOr).
// ---------------------------------------------------------------------------
__global__ __launch_bounds__(256)
void filter_kernel(const float4* __restrict__ box8,
                   unsigned long long* __restrict__ mask,
                   unsigned long long* __restrict__ summary,
                   int n, int words, int swz)
{
    int i = blockIdx.y;
    int jbase = blockIdx.x * 256;
    if (jbase + 255 <= i) return;
    int j = jbase + threadIdx.x;
    if (j >= n || j <= i) return;

    float4 A0 = box8[2 * i], A1 = box8[2 * i + 1];   // uniform -> s_load
    float4 B0 = box8[2 * j], B1 = box8[2 * j + 1];

    float dx = A0.x - B0.x, dy = A0.y - B0.y;
    float rr = A1.z + B1.z + 1e-2f;
    if (dx * dx + dy * dy > rr * rr) return;         // disjoint -> inter == 0

    float a1 = A1.w, a2 = B1.w;
    float amin = fminf(a1, a2), amax = fmaxf(a1, a2);
    if (amin < 0.699f * amax) return;                // iou bound < threshold

    float inter = rect_inter_area_cs(A0.x, A0.y, A0.z, A0.w, A1.x, A1.y,
                                     B0.x, B0.y, B0.z, B0.w, B1.x, B1.y);
    float iou = inter / (a1 + a2 - inter + EPSF);
    if (iou >= NMS_THR) {
        int slot = (j >> 6) ^ (i & swz);
        atomicOr(&mask[(size_t)i * words + slot], 1ULL << (j & 63));
        atomicOr(&summary[i >> 6], 1ULL << (i & 63));
    }
}

__device__ __forceinline__ unsigned long long rl64(unsigned long long v, int l) {
    unsigned int lo = (unsigned int)__builtin_amdgcn_readlane((int)(unsigned int)v, l);
    unsigned int hi = (unsigned int)__builtin_amdgcn_readlane((int)(v >> 32), l);
    return ((unsigned long long)hi << 32) | lo;
}

// ---------------------------------------------------------------------------
// Greedy NMS, one wave. Per 64-box chunk:
//   parallel fast path: if no candidate row suppresses within its own chunk
//   (ballot of diagonal word D) and TOPN headroom, keepmask = ~cw & valid,
//   stored with one prefix-popcount coalesced store. Serial 64-iter scan only
//   for coupled chunks / TOPN boundary (rare). OR-into-acc touches only rows
//   flagged nonzero by the summary bitmap. Chunks streamed 2-deep into 3 LDS
//   buffers via global_load_lds with counted vmcnt(16); break at cnt==TOPN.
// Assumes words even, words<=32, chunks<=64 (n=2048 -> 32/32).
// ---------------------------------------------------------------------------
__global__ __launch_bounds__(64, 1)
void greedy_kernel(const unsigned long long* __restrict__ mask,
                   const unsigned long long* __restrict__ summary,
                   int* __restrict__ keep, int n, int words, int swz)
{
    __shared__ __align__(16) unsigned long long lds[3 * 2048]; // 48 KB
    const int lane = threadIdx.x;
    const int g = lane >> 5;
    const int w = lane & 31;
    const int chunks = (n + 63) >> 6;
    const int cbytes = 64 * words * 8;            // <= 16 KB, mult of 1024
    const int nloads = cbytes >> 10;              // 1 KB per gl_lds instr

    auto stage = [&](int c) {
        const char* src = (const char*)mask + (size_t)c * cbytes
                        + (size_t)lane * 16;
        char* dst = (char*)&lds[(size_t)(c % 3) * 2048];
        for (int t = 0; t < nloads; ++t)
            __builtin_amdgcn_global_load_lds(
                (const GLOBAL_AS unsigned int*)(src + t * 1024),
                (LDS_AS unsigned int*)(dst + t * 1024), 16, 0, 0);
    };

    stage(0);
    if (chunks > 1) stage(1);

    unsigned long long szv = (lane < chunks) ? summary[lane] : 0ULL;

    unsigned long long acc = 0ULL;   // lane (g,w): OR of kept rows' word w
    int cnt = 0;

    for (int c = 0; c < chunks; ++c) {
        if (cnt >= TOPN) break;
        if (c + 1 < chunks) { asm volatile("s_waitcnt vmcnt(16)" ::: "memory"); }
        else                { asm volatile("s_waitcnt vmcnt(0)"  ::: "memory"); }
        __builtin_amdgcn_sched_barrier(0);
        if (c + 2 < chunks) stage(c + 2);

        const int base = c << 6;
        unsigned long long cw = rl64(acc, c) | rl64(acc, 32 + c);
        unsigned long long D =
            lds[(size_t)(c % 3) * 2048 + (size_t)lane * words + (c ^ (lane & swz))];

        unsigned long long valid =
            (n - base >= 64) ? ~0ULL : ((1ULL << (n - base)) - 1ULL);
        unsigned long long cand = ~cw & valid;
        unsigned long long intra = __ballot(D != 0ULL);
        int rem = TOPN - cnt;

        unsigned long long kmask;
        if ((intra & cand) == 0ULL && __popcll(cand) <= rem) {
            kmask = cand;                          // parallel decision
        } else {
            kmask = 0ULL;                          // serial fallback (rare)
            int cl = cnt;
#pragma unroll
            for (int k = 0; k < 64; ++k) {
                if (!((cw >> k) & 1ULL) && cl < TOPN && (base + k) < n) {
                    cw |= rl64(D, k);              // literal lane index
                    kmask |= (1ULL << k);
                    ++cl;
                }
            }
        }

        if ((kmask >> lane) & 1ULL)
            keep[cnt + __popcll(kmask & ((1ULL << lane) - 1ULL))] = base + lane;
        cnt += __popcll(kmask);

        // OR kept nonzero rows into distributed acc (groups split rows)
        unsigned long long orrows = kmask & rl64(szv, c);
        while (orrows) {
            int r = (int)__builtin_ctzll(orrows);
            orrows &= orrows - 1ULL;
            unsigned long long v = 0ULL;
            if (g == (r & 1))
                v = lds[(size_t)(c % 3) * 2048 + (size_t)r * words
                        + (w ^ (r & swz))];
            acc |= v;
        }
    }
    asm volatile("s_waitcnt vmcnt(0)" ::: "memory");

    for (int t = cnt + lane; t < TOPN; t += 64) keep[t] = -1;
}

extern "C" void kernel_launch(void* const* d_in, const int* in_sizes, int n_in,
                              void* d_out, int out_size, void* d_ws, size_t ws_size,
                              hipStream_t stream) {
    const float* boxes = (const float*)d_in[0];
    int n = in_sizes[0] / 5;                     // 2048
    int words = (n + 63) / 64;                   // 32
    int chunks = (n + 63) / 64;
    int swz = (words == 32) ? 31 : 0;
    int* keep = (int*)d_out;

    // ws layout: mask (chunks*64*words*8, rounded so streaming never OOB) |
    //            summary (512B) | box8 (n*32B)
    unsigned long long* mask = (unsigned long long*)d_ws;
    size_t mask_alloc = (size_t)chunks * 64 * words * 8;
    unsigned long long* summary =
        (unsigned long long*)((char*)d_ws + mask_alloc);
    float4* box8 = (float4*)((char*)d_ws + mask_alloc + 512);

    hipMemsetAsync(mask, 0, mask_alloc + 512, stream);

    prep_kernel<<<(n + 255) / 256, 256, 0, stream>>>(boxes, box8, n);

    dim3 grid((n + 255) / 256, n);
    filter_kernel<<<grid, 256, 0, stream>>>(box8, mask, summary, n, words, swz);
    greedy_kernel<<<1, 64, 0, stream>>>(mask, summary, keep, n, words, swz);
}

// Round 6
// 35.431 us; speedup vs baseline: 7.6569x; 1.8231x over previous
//
#include <hip/hip_runtime.h>
#include <hip/hip_bf16.h>

#define CAP 8
#define EPSF 1e-8f
#define NMS_THR 0.7f
#define TOPN 1000
#define ITILE 16                      // i-rows per block tile
#define QCAP (256 * ITILE)            // worst-case survivors per tile: no overflow

#define GLOBAL_AS __attribute__((address_space(1)))
#define LDS_AS    __attribute__((address_space(3)))

// ---------------------------------------------------------------------------
// Rotated-rect intersection area from center/size/cos/sin. Faithful fp32 port
// of the reference Sutherland-Hodgman clip (crossing-before-current emission,
// denom clamped to +EPS, CAP=8 truncation, shoelace with abs). ALL indices
// compile-time -> zero scratch, fully branchless. Verified absmax==0 R1-R5.
// ---------------------------------------------------------------------------
__device__ __forceinline__ float rect_inter_area_cs(
    float xc1, float yc1, float w1, float h1, float c1, float s1,
    float xc2, float yc2, float w2, float h2, float c2, float s2)
{
    float px[CAP], py[CAP];
    {
        float lx0 = -0.5f * w1, lx1 = 0.5f * w1;
        float ly0 = -0.5f * h1, ly1 = 0.5f * h1;
        px[0] = xc1 + lx0 * c1 - ly0 * s1;  py[0] = yc1 + lx0 * s1 + ly0 * c1;
        px[1] = xc1 + lx1 * c1 - ly0 * s1;  py[1] = yc1 + lx1 * s1 + ly0 * c1;
        px[2] = xc1 + lx1 * c1 - ly1 * s1;  py[2] = yc1 + lx1 * s1 + ly1 * c1;
        px[3] = xc1 + lx0 * c1 - ly1 * s1;  py[3] = yc1 + lx0 * s1 + ly1 * c1;
#pragma unroll
        for (int s2i = 4; s2i < CAP; ++s2i) { px[s2i] = 0.f; py[s2i] = 0.f; }
    }
    float qx[4], qy[4];
    {
        float lx0 = -0.5f * w2, lx1 = 0.5f * w2;
        float ly0 = -0.5f * h2, ly1 = 0.5f * h2;
        qx[0] = xc2 + lx0 * c2 - ly0 * s2;  qy[0] = yc2 + lx0 * s2 + ly0 * c2;
        qx[1] = xc2 + lx1 * c2 - ly0 * s2;  qy[1] = yc2 + lx1 * s2 + ly0 * c2;
        qx[2] = xc2 + lx1 * c2 - ly1 * s2;  qy[2] = yc2 + lx1 * s2 + ly1 * c2;
        qx[3] = xc2 + lx0 * c2 - ly1 * s2;  qy[3] = yc2 + lx0 * s2 + ly1 * c2;
    }

    int n = 4;
#pragma unroll
    for (int e = 0; e < 4; ++e) {
        float p0x = qx[e], p0y = qy[e];
        float ex = qx[(e + 1) & 3] - p0x, ey = qy[(e + 1) & 3] - p0y;

        float pxp = px[0], pyp = py[0];
#pragma unroll
        for (int s = 1; s < CAP; ++s)
            if (s == n - 1) { pxp = px[s]; pyp = py[s]; }
        float dp = ex * (pyp - p0y) - ey * (pxp - p0x);

        float nx_[CAP], ny_[CAP];
#pragma unroll
        for (int s = 0; s < CAP; ++s) { nx_[s] = 0.f; ny_[s] = 0.f; }
        int m = 0;

#pragma unroll
        for (int k = 0; k < CAP; ++k) {
            bool act = (k < n);
            float pxc = px[k], pyc = py[k];
            float dc = ex * (pyc - p0y) - ey * (pxc - p0x);
            bool cin = (dc >= 0.0f), pin = (dp >= 0.0f);

            float den = dp - dc;
            den = (fabsf(den) < EPSF) ? EPSF : den;
            float t = dp / den;
            float ix = pxp + t * (pxc - pxp);
            float iy = pyp + t * (pyc - pyp);

            bool emit_cross = act && (cin != pin);
            if (emit_cross) {
#pragma unroll
                for (int s = 0; s < CAP; ++s)
                    if (s == m) { nx_[s] = ix; ny_[s] = iy; }
                ++m;
            }
            bool emit_cur = act && cin;
            if (emit_cur) {
#pragma unroll
                for (int s = 0; s < CAP; ++s)
                    if (s == m) { nx_[s] = pxc; ny_[s] = pyc; }
                ++m;
            }
            if (act) { pxp = pxc; pyp = pyc; dp = dc; }
        }
        n = (m < CAP) ? m : CAP;
#pragma unroll
        for (int s = 0; s < CAP; ++s) { px[s] = nx_[s]; py[s] = ny_[s]; }
    }

    if (n < 3) return 0.0f;
    float s = 0.0f;
#pragma unroll
    for (int k = 0; k < CAP; ++k) {
        if (k < n) {
            float nxk = px[(k + 1) & (CAP - 1)];
            float nyk = py[(k + 1) & (CAP - 1)];
            if (k == n - 1) { nxk = px[0]; nyk = py[0]; }
            s += px[k] * nyk - py[k] * nxk;
        }
    }
    return 0.5f * fabsf(s);
}

// ---------------------------------------------------------------------------
// Prep: per-box [x,y,w,h | cos,sin, r=half-diag, area] as 2x float4 (32B).
// ---------------------------------------------------------------------------
__global__ __launch_bounds__(256)
void prep_kernel(const float* __restrict__ boxes, float4* __restrict__ box8,
                 int n)
{
    int i = blockIdx.x * 256 + threadIdx.x;
    if (i >= n) return;
    const float* b = boxes + (size_t)i * 5;
    float x = b[0], y = b[1], w = b[2], h = b[3], t = b[4];
    box8[2 * i]     = make_float4(x, y, w, h);
    box8[2 * i + 1] = make_float4(cosf(t), sinf(t),
                                  0.5f * sqrtf(w * w + h * h), w * h);
}

// ---------------------------------------------------------------------------
// Pair kernel, tiled: block = 256 j-lanes x ITILE i-rows. j-box held in
// registers across the i-sweep; i-boxes broadcast from a 512B LDS A-tile.
// Survivors (cheap-reject passers, ~1.5%) go to a block-local LDS queue;
// after the sweep ALL 256 lanes drain the queue, so the expensive clip runs
// one-pair-per-lane at full utilization (no 1-lane-per-wave divergence).
// QCAP == tile pair count -> overflow impossible. Mask word index
// XOR-swizzled by (i&swz) (write-side; greedy reads with same swizzle).
// ---------------------------------------------------------------------------
__global__ __launch_bounds__(256)
void filter_kernel(const float4* __restrict__ box8,
                   unsigned long long* __restrict__ mask,
                   unsigned long long* __restrict__ summary,
                   int n, int words, int swz)
{
    const int jt = blockIdx.x, it = blockIdx.y;
    const int i0 = it * ITILE;
    if (i0 >= jt * 256 + 255) return;            // dead tile: no pair j > i
    const int j = jt * 256 + threadIdx.x;

    __shared__ float4 atile[2 * ITILE];
    __shared__ unsigned int q[QCAP];
    __shared__ int qcnt;

    if (threadIdx.x == 0) qcnt = 0;
    if (threadIdx.x < 2 * ITILE) {
        int src = 2 * i0 + threadIdx.x;
        atile[threadIdx.x] = (src < 2 * n) ? box8[src]
                                           : make_float4(0.f, 0.f, 0.f, 0.f);
    }
    __syncthreads();

    float4 B0, B1;
    bool jok = (j < n);
    if (jok) { B0 = box8[2 * j]; B1 = box8[2 * j + 1]; }
    else     { B0 = make_float4(0,0,0,0); B1 = make_float4(0,0,0,0); }

#pragma unroll
    for (int ii = 0; ii < ITILE; ++ii) {
        int i = i0 + ii;
        float4 A0 = atile[2 * ii], A1 = atile[2 * ii + 1];  // LDS broadcast
        bool pass = jok && (j > i) && (i < n);
        float dx = A0.x - B0.x, dy = A0.y - B0.y;
        float rr = A1.z + B1.z + 1e-2f;
        pass = pass && (dx * dx + dy * dy <= rr * rr);
        float amin = fminf(A1.w, B1.w), amax = fmaxf(A1.w, B1.w);
        pass = pass && (amin >= 0.699f * amax);
        if (pass) {
            int idx = atomicAdd(&qcnt, 1);       // LDS atomic, rare
            q[idx] = ((unsigned int)i << 16) | (unsigned int)j;
        }
    }
    __syncthreads();

    int qn = qcnt;                               // <= QCAP by construction
    for (int t = threadIdx.x; t < qn; t += 256) {
        unsigned int pk = q[t];
        int i2 = (int)(pk >> 16), j2 = (int)(pk & 0xffffu);
        float4 A0 = box8[2 * i2], A1 = box8[2 * i2 + 1];
        float4 C0 = box8[2 * j2], C1 = box8[2 * j2 + 1];
        float a1 = A1.w, a2 = C1.w;
        float inter = rect_inter_area_cs(A0.x, A0.y, A0.z, A0.w, A1.x, A1.y,
                                         C0.x, C0.y, C0.z, C0.w, C1.x, C1.y);
        float iou = inter / (a1 + a2 - inter + EPSF);
        if (iou >= NMS_THR) {
            int slot = (j2 >> 6) ^ (i2 & swz);
            atomicOr(&mask[(size_t)i2 * words + slot], 1ULL << (j2 & 63));
            atomicOr(&summary[i2 >> 6], 1ULL << (i2 & 63));
        }
    }
}

__device__ __forceinline__ unsigned long long rl64(unsigned long long v, int l) {
    unsigned int lo = (unsigned int)__builtin_amdgcn_readlane((int)(unsigned int)v, l);
    unsigned int hi = (unsigned int)__builtin_amdgcn_readlane((int)(v >> 32), l);
    return ((unsigned long long)hi << 32) | lo;
}

// ---------------------------------------------------------------------------
// Greedy NMS, one wave (unchanged from R5: parallel fast path + serial
// fallback for coupled chunks, summary-gated OR, 2-deep LDS streaming).
// ---------------------------------------------------------------------------
__global__ __launch_bounds__(64, 1)
void greedy_kernel(const unsigned long long* __restrict__ mask,
                   const unsigned long long* __restrict__ summary,
                   int* __restrict__ keep, int n, int words, int swz)
{
    __shared__ __align__(16) unsigned long long lds[3 * 2048]; // 48 KB
    const int lane = threadIdx.x;
    const int g = lane >> 5;
    const int w = lane & 31;
    const int chunks = (n + 63) >> 6;
    const int cbytes = 64 * words * 8;            // <= 16 KB, mult of 1024
    const int nloads = cbytes >> 10;              // 1 KB per gl_lds instr

    auto stage = [&](int c) {
        const char* src = (const char*)mask + (size_t)c * cbytes
                        + (size_t)lane * 16;
        char* dst = (char*)&lds[(size_t)(c % 3) * 2048];
        for (int t = 0; t < nloads; ++t)
            __builtin_amdgcn_global_load_lds(
                (const GLOBAL_AS unsigned int*)(src + t * 1024),
                (LDS_AS unsigned int*)(dst + t * 1024), 16, 0, 0);
    };

    stage(0);
    if (chunks > 1) stage(1);

    unsigned long long szv = (lane < chunks) ? summary[lane] : 0ULL;

    unsigned long long acc = 0ULL;   // lane (g,w): OR of kept rows' word w
    int cnt = 0;

    for (int c = 0; c < chunks; ++c) {
        if (cnt >= TOPN) break;
        if (c + 1 < chunks) { asm volatile("s_waitcnt vmcnt(16)" ::: "memory"); }
        else                { asm volatile("s_waitcnt vmcnt(0)"  ::: "memory"); }
        __builtin_amdgcn_sched_barrier(0);
        if (c + 2 < chunks) stage(c + 2);

        const int base = c << 6;
        unsigned long long cw = rl64(acc, c) | rl64(acc, 32 + c);
        unsigned long long D =
            lds[(size_t)(c % 3) * 2048 + (size_t)lane * words + (c ^ (lane & swz))];

        unsigned long long valid =
            (n - base >= 64) ? ~0ULL : ((1ULL << (n - base)) - 1ULL);
        unsigned long long cand = ~cw & valid;
        unsigned long long intra = __ballot(D != 0ULL);
        int rem = TOPN - cnt;

        unsigned long long kmask;
        if ((intra & cand) == 0ULL && __popcll(cand) <= rem) {
            kmask = cand;                          // parallel decision
        } else {
            kmask = 0ULL;                          // serial fallback (rare)
            int cl = cnt;
#pragma unroll
            for (int k = 0; k < 64; ++k) {
                if (!((cw >> k) & 1ULL) && cl < TOPN && (base + k) < n) {
                    cw |= rl64(D, k);              // literal lane index
                    kmask |= (1ULL << k);
                    ++cl;
                }
            }
        }

        if ((kmask >> lane) & 1ULL)
            keep[cnt + __popcll(kmask & ((1ULL << lane) - 1ULL))] = base + lane;
        cnt += __popcll(kmask);

        // OR kept nonzero rows into distributed acc (groups split rows)
        unsigned long long orrows = kmask & rl64(szv, c);
        while (orrows) {
            int r = (int)__builtin_ctzll(orrows);
            orrows &= orrows - 1ULL;
            unsigned long long v = 0ULL;
            if (g == (r & 1))
                v = lds[(size_t)(c % 3) * 2048 + (size_t)r * words
                        + (w ^ (r & swz))];
            acc |= v;
        }
    }
    asm volatile("s_waitcnt vmcnt(0)" ::: "memory");

    for (int t = cnt + lane; t < TOPN; t += 64) keep[t] = -1;
}

extern "C" void kernel_launch(void* const* d_in, const int* in_sizes, int n_in,
                              void* d_out, int out_size, void* d_ws, size_t ws_size,
                              hipStream_t stream) {
    const float* boxes = (const float*)d_in[0];
    int n = in_sizes[0] / 5;                     // 2048
    int words = (n + 63) / 64;                   // 32
    int chunks = (n + 63) / 64;
    int swz = (words == 32) ? 31 : 0;
    int* keep = (int*)d_out;

    // ws layout: mask (chunks*64*words*8) | summary (512B) | box8 (n*32B)
    unsigned long long* mask = (unsigned long long*)d_ws;
    size_t mask_alloc = (size_t)chunks * 64 * words * 8;
    unsigned long long* summary =
        (unsigned long long*)((char*)d_ws + mask_alloc);
    float4* box8 = (float4*)((char*)d_ws + mask_alloc + 512);

    hipMemsetAsync(mask, 0, mask_alloc + 512, stream);

    prep_kernel<<<(n + 255) / 256, 256, 0, stream>>>(boxes, box8, n);

    dim3 grid((n + 255) / 256, (n + ITILE - 1) / ITILE);
    filter_kernel<<<grid, 256, 0, stream>>>(box8, mask, summary, n, words, swz);
    greedy_kernel<<<1, 64, 0, stream>>>(mask, summary, keep, n, words, swz);
}

// Round 7
// 33.776 us; speedup vs baseline: 8.0320x; 1.0490x over previous
//
#include <hip/hip_runtime.h>
#include <hip/hip_bf16.h>

#define CAP 8
#define EPSF 1e-8f
#define NMS_THR 0.7f
#define TOPN 1000
#define ITILE 16                      // i-rows per block tile
#define QCAP (256 * ITILE)            // worst-case survivors per tile: no overflow

#define GLOBAL_AS __attribute__((address_space(1)))
#define LDS_AS    __attribute__((address_space(3)))

// ---------------------------------------------------------------------------
// Rotated-rect intersection area from center/size/cos/sin. Faithful fp32 port
// of the reference Sutherland-Hodgman clip (crossing-before-current emission,
// denom clamped to +EPS, CAP=8 truncation, shoelace with abs). ALL indices
// compile-time -> zero scratch, fully branchless. Verified absmax==0 R1-R6.
// ---------------------------------------------------------------------------
__device__ __forceinline__ float rect_inter_area_cs(
    float xc1, float yc1, float w1, float h1, float c1, float s1,
    float xc2, float yc2, float w2, float h2, float c2, float s2)
{
    float px[CAP], py[CAP];
    {
        float lx0 = -0.5f * w1, lx1 = 0.5f * w1;
        float ly0 = -0.5f * h1, ly1 = 0.5f * h1;
        px[0] = xc1 + lx0 * c1 - ly0 * s1;  py[0] = yc1 + lx0 * s1 + ly0 * c1;
        px[1] = xc1 + lx1 * c1 - ly0 * s1;  py[1] = yc1 + lx1 * s1 + ly0 * c1;
        px[2] = xc1 + lx1 * c1 - ly1 * s1;  py[2] = yc1 + lx1 * s1 + ly1 * c1;
        px[3] = xc1 + lx0 * c1 - ly1 * s1;  py[3] = yc1 + lx0 * s1 + ly1 * c1;
#pragma unroll
        for (int s2i = 4; s2i < CAP; ++s2i) { px[s2i] = 0.f; py[s2i] = 0.f; }
    }
    float qx[4], qy[4];
    {
        float lx0 = -0.5f * w2, lx1 = 0.5f * w2;
        float ly0 = -0.5f * h2, ly1 = 0.5f * h2;
        qx[0] = xc2 + lx0 * c2 - ly0 * s2;  qy[0] = yc2 + lx0 * s2 + ly0 * c2;
        qx[1] = xc2 + lx1 * c2 - ly0 * s2;  qy[1] = yc2 + lx1 * s2 + ly0 * c2;
        qx[2] = xc2 + lx1 * c2 - ly1 * s2;  qy[2] = yc2 + lx1 * s2 + ly1 * c2;
        qx[3] = xc2 + lx0 * c2 - ly1 * s2;  qy[3] = yc2 + lx0 * s2 + ly1 * c2;
    }

    int n = 4;
#pragma unroll
    for (int e = 0; e < 4; ++e) {
        float p0x = qx[e], p0y = qy[e];
        float ex = qx[(e + 1) & 3] - p0x, ey = qy[(e + 1) & 3] - p0y;

        float pxp = px[0], pyp = py[0];
#pragma unroll
        for (int s = 1; s < CAP; ++s)
            if (s == n - 1) { pxp = px[s]; pyp = py[s]; }
        float dp = ex * (pyp - p0y) - ey * (pxp - p0x);

        float nx_[CAP], ny_[CAP];
#pragma unroll
        for (int s = 0; s < CAP; ++s) { nx_[s] = 0.f; ny_[s] = 0.f; }
        int m = 0;

#pragma unroll
        for (int k = 0; k < CAP; ++k) {
            bool act = (k < n);
            float pxc = px[k], pyc = py[k];
            float dc = ex * (pyc - p0y) - ey * (pxc - p0x);
            bool cin = (dc >= 0.0f), pin = (dp >= 0.0f);

            float den = dp - dc;
            den = (fabsf(den) < EPSF) ? EPSF : den;
            float t = dp / den;
            float ix = pxp + t * (pxc - pxp);
            float iy = pyp + t * (pyc - pyp);

            bool emit_cross = act && (cin != pin);
            if (emit_cross) {
#pragma unroll
                for (int s = 0; s < CAP; ++s)
                    if (s == m) { nx_[s] = ix; ny_[s] = iy; }
                ++m;
            }
            bool emit_cur = act && cin;
            if (emit_cur) {
#pragma unroll
                for (int s = 0; s < CAP; ++s)
                    if (s == m) { nx_[s] = pxc; ny_[s] = pyc; }
                ++m;
            }
            if (act) { pxp = pxc; pyp = pyc; dp = dc; }
        }
        n = (m < CAP) ? m : CAP;
#pragma unroll
        for (int s = 0; s < CAP; ++s) { px[s] = nx_[s]; py[s] = ny_[s]; }
    }

    if (n < 3) return 0.0f;
    float s = 0.0f;
#pragma unroll
    for (int k = 0; k < CAP; ++k) {
        if (k < n) {
            float nxk = px[(k + 1) & (CAP - 1)];
            float nyk = py[(k + 1) & (CAP - 1)];
            if (k == n - 1) { nxk = px[0]; nyk = py[0]; }
            s += px[k] * nyk - py[k] * nxk;
        }
    }
    return 0.5f * fabsf(s);
}

// ---------------------------------------------------------------------------
// Init: fused memset + prep. Thread t zeros mask row t (ulonglong2 stores),
// threads <64 zero the summary words, threads <n compute
// box8[t] = [x,y,w,h | cos,sin, r=half-diag, area]. Replaces two graph nodes
// (fillBuffer + prep) with one ~1us kernel.
// ---------------------------------------------------------------------------
__global__ __launch_bounds__(256)
void init_kernel(const float* __restrict__ boxes, float4* __restrict__ box8,
                 ulonglong2* __restrict__ maskv,
                 unsigned long long* __restrict__ summary,
                 int n, int rows_total, int words)
{
    int t = blockIdx.x * 256 + threadIdx.x;
    if (t < rows_total) {
        ulonglong2 z; z.x = 0ULL; z.y = 0ULL;
        ulonglong2* p = maskv + (size_t)t * (words >> 1);
        for (int k = 0; k < (words >> 1); ++k) p[k] = z;
    }
    if (t < 64) summary[t] = 0ULL;
    if (t < n) {
        const float* b = boxes + (size_t)t * 5;
        float x = b[0], y = b[1], w = b[2], h = b[3], th = b[4];
        box8[2 * t]     = make_float4(x, y, w, h);
        box8[2 * t + 1] = make_float4(cosf(th), sinf(th),
                                      0.5f * sqrtf(w * w + h * h), w * h);
    }
}

// ---------------------------------------------------------------------------
// Pair kernel, tiled (verified R6): block = 256 j-lanes x ITILE i-rows.
// j-box in registers across the i-sweep; i-boxes broadcast from LDS A-tile.
// Cheap-reject survivors go to a block-local LDS queue; all 256 lanes drain
// it so the expensive clip runs one-pair-per-lane (no divergence waste).
// Mask word index XOR-swizzled by (i&swz) (write-side; greedy reads same).
// ---------------------------------------------------------------------------
__global__ __launch_bounds__(256)
void filter_kernel(const float4* __restrict__ box8,
                   unsigned long long* __restrict__ mask,
                   unsigned long long* __restrict__ summary,
                   int n, int words, int swz)
{
    const int jt = blockIdx.x, it = blockIdx.y;
    const int i0 = it * ITILE;
    if (i0 >= jt * 256 + 255) return;            // dead tile: no pair j > i
    const int j = jt * 256 + threadIdx.x;

    __shared__ float4 atile[2 * ITILE];
    __shared__ unsigned int q[QCAP];
    __shared__ int qcnt;

    if (threadIdx.x == 0) qcnt = 0;
    if (threadIdx.x < 2 * ITILE) {
        int src = 2 * i0 + threadIdx.x;
        atile[threadIdx.x] = (src < 2 * n) ? box8[src]
                                           : make_float4(0.f, 0.f, 0.f, 0.f);
    }
    __syncthreads();

    float4 B0, B1;
    bool jok = (j < n);
    if (jok) { B0 = box8[2 * j]; B1 = box8[2 * j + 1]; }
    else     { B0 = make_float4(0,0,0,0); B1 = make_float4(0,0,0,0); }

#pragma unroll
    for (int ii = 0; ii < ITILE; ++ii) {
        int i = i0 + ii;
        float4 A0 = atile[2 * ii], A1 = atile[2 * ii + 1];  // LDS broadcast
        bool pass = jok && (j > i) && (i < n);
        float dx = A0.x - B0.x, dy = A0.y - B0.y;
        float rr = A1.z + B1.z + 1e-2f;
        pass = pass && (dx * dx + dy * dy <= rr * rr);
        float amin = fminf(A1.w, B1.w), amax = fmaxf(A1.w, B1.w);
        pass = pass && (amin >= 0.699f * amax);
        if (pass) {
            int idx = atomicAdd(&qcnt, 1);       // LDS atomic, rare
            q[idx] = ((unsigned int)i << 16) | (unsigned int)j;
        }
    }
    __syncthreads();

    int qn = qcnt;                               // <= QCAP by construction
    for (int t = threadIdx.x; t < qn; t += 256) {
        unsigned int pk = q[t];
        int i2 = (int)(pk >> 16), j2 = (int)(pk & 0xffffu);
        float4 A0 = box8[2 * i2], A1 = box8[2 * i2 + 1];
        float4 C0 = box8[2 * j2], C1 = box8[2 * j2 + 1];
        float a1 = A1.w, a2 = C1.w;
        float inter = rect_inter_area_cs(A0.x, A0.y, A0.z, A0.w, A1.x, A1.y,
                                         C0.x, C0.y, C0.z, C0.w, C1.x, C1.y);
        float iou = inter / (a1 + a2 - inter + EPSF);
        if (iou >= NMS_THR) {
            int slot = (j2 >> 6) ^ (i2 & swz);
            atomicOr(&mask[(size_t)i2 * words + slot], 1ULL << (j2 & 63));
            atomicOr(&summary[i2 >> 6], 1ULL << (i2 & 63));
        }
    }
}

__device__ __forceinline__ unsigned long long rl64(unsigned long long v, int l) {
    unsigned int lo = (unsigned int)__builtin_amdgcn_readlane((int)(unsigned int)v, l);
    unsigned int hi = (unsigned int)__builtin_amdgcn_readlane((int)(v >> 32), l);
    return ((unsigned long long)hi << 32) | lo;
}

// ---------------------------------------------------------------------------
// Greedy NMS, one wave (verified R5/R6 structure). One change: the serial
// fallback now triggers only when a candidate row suppresses a box that is
// STILL a candidate (D & cand), not on any intra-chunk bit — strictly weaker
// trigger, still conservative (fallback itself is fully general).
// ---------------------------------------------------------------------------
__global__ __launch_bounds__(64, 1)
void greedy_kernel(const unsigned long long* __restrict__ mask,
                   const unsigned long long* __restrict__ summary,
                   int* __restrict__ keep, int n, int words, int swz)
{
    __shared__ __align__(16) unsigned long long lds[3 * 2048]; // 48 KB
    const int lane = threadIdx.x;
    const int g = lane >> 5;
    const int w = lane & 31;
    const int chunks = (n + 63) >> 6;
    const int cbytes = 64 * words * 8;            // <= 16 KB, mult of 1024
    const int nloads = cbytes >> 10;              // 1 KB per gl_lds instr

    auto stage = [&](int c) {
        const char* src = (const char*)mask + (size_t)c * cbytes
                        + (size_t)lane * 16;
        char* dst = (char*)&lds[(size_t)(c % 3) * 2048];
        for (int t = 0; t < nloads; ++t)
            __builtin_amdgcn_global_load_lds(
                (const GLOBAL_AS unsigned int*)(src + t * 1024),
                (LDS_AS unsigned int*)(dst + t * 1024), 16, 0, 0);
    };

    stage(0);
    if (chunks > 1) stage(1);

    unsigned long long szv = (lane < chunks) ? summary[lane] : 0ULL;

    unsigned long long acc = 0ULL;   // lane (g,w): OR of kept rows' word w
    int cnt = 0;

    for (int c = 0; c < chunks; ++c) {
        if (cnt >= TOPN) break;
        if (c + 1 < chunks) { asm volatile("s_waitcnt vmcnt(16)" ::: "memory"); }
        else                { asm volatile("s_waitcnt vmcnt(0)"  ::: "memory"); }
        __builtin_amdgcn_sched_barrier(0);
        if (c + 2 < chunks) stage(c + 2);

        const int base = c << 6;
        unsigned long long cw = rl64(acc, c) | rl64(acc, 32 + c);
        unsigned long long D =
            lds[(size_t)(c % 3) * 2048 + (size_t)lane * words + (c ^ (lane & swz))];

        unsigned long long valid =
            (n - base >= 64) ? ~0ULL : ((1ULL << (n - base)) - 1ULL);
        unsigned long long cand = ~cw & valid;
        unsigned long long intra = __ballot((D & cand) != 0ULL);
        int rem = TOPN - cnt;

        unsigned long long kmask;
        if ((intra & cand) == 0ULL && __popcll(cand) <= rem) {
            kmask = cand;                          // parallel decision
        } else {
            kmask = 0ULL;                          // serial fallback (rare)
            int cl = cnt;
#pragma unroll
            for (int k = 0; k < 64; ++k) {
                if (!((cw >> k) & 1ULL) && cl < TOPN && (base + k) < n) {
                    cw |= rl64(D, k);              // literal lane index
                    kmask |= (1ULL << k);
                    ++cl;
                }
            }
        }

        if ((kmask >> lane) & 1ULL)
            keep[cnt + __popcll(kmask & ((1ULL << lane) - 1ULL))] = base + lane;
        cnt += __popcll(kmask);

        // OR kept nonzero rows into distributed acc (groups split rows)
        unsigned long long orrows = kmask & rl64(szv, c);
        while (orrows) {
            int r = (int)__builtin_ctzll(orrows);
            orrows &= orrows - 1ULL;
            unsigned long long v = 0ULL;
            if (g == (r & 1))
                v = lds[(size_t)(c % 3) * 2048 + (size_t)r * words
                        + (w ^ (r & swz))];
            acc |= v;
        }
    }
    asm volatile("s_waitcnt vmcnt(0)" ::: "memory");

    for (int t = cnt + lane; t < TOPN; t += 64) keep[t] = -1;
}

extern "C" void kernel_launch(void* const* d_in, const int* in_sizes, int n_in,
                              void* d_out, int out_size, void* d_ws, size_t ws_size,
                              hipStream_t stream) {
    const float* boxes = (const float*)d_in[0];
    int n = in_sizes[0] / 5;                     // 2048
    int words = (n + 63) / 64;                   // 32
    int chunks = (n + 63) / 64;
    int rows_total = chunks * 64;                // 2048
    int swz = (words == 32) ? 31 : 0;
    int* keep = (int*)d_out;

    // ws layout: mask (rows_total*words*8) | summary (512B) | box8 (n*32B)
    unsigned long long* mask = (unsigned long long*)d_ws;
    size_t mask_alloc = (size_t)rows_total * words * 8;
    unsigned long long* summary =
        (unsigned long long*)((char*)d_ws + mask_alloc);
    float4* box8 = (float4*)((char*)d_ws + mask_alloc + 512);

    init_kernel<<<(rows_total + 255) / 256, 256, 0, stream>>>(
        boxes, box8, (ulonglong2*)mask, summary, n, rows_total, words);

    dim3 grid((n + 255) / 256, (n + ITILE - 1) / ITILE);
    filter_kernel<<<grid, 256, 0, stream>>>(box8, mask, summary, n, words, swz);
    greedy_kernel<<<1, 64, 0, stream>>>(mask, summary, keep, n, words, swz);
}

// Round 8
// 28.957 us; speedup vs baseline: 9.3687x; 1.1664x over previous
//
#include <hip/hip_runtime.h>
#include <hip/hip_bf16.h>

#define CAP 8
#define EPSF 1e-8f
#define NMS_THR 0.7f
#define TOPN 1000
#define ITILE 16                      // i-rows per block tile
#define QCAP (256 * ITILE)            // worst-case survivors per tile: no overflow
#define CAPR 480                      // max nonzero rows cached in LDS (480*256B)

#define GLOBAL_AS __attribute__((address_space(1)))
#define LDS_AS    __attribute__((address_space(3)))

// ---------------------------------------------------------------------------
// Rotated-rect intersection area from center/size/cos/sin. Faithful fp32 port
// of the reference Sutherland-Hodgman clip (crossing-before-current emission,
// denom clamped to +EPS, CAP=8 truncation, shoelace with abs). ALL indices
// compile-time -> zero scratch, fully branchless. Verified absmax==0 R1-R7.
// ---------------------------------------------------------------------------
__device__ __forceinline__ float rect_inter_area_cs(
    float xc1, float yc1, float w1, float h1, float c1, float s1,
    float xc2, float yc2, float w2, float h2, float c2, float s2)
{
    float px[CAP], py[CAP];
    {
        float lx0 = -0.5f * w1, lx1 = 0.5f * w1;
        float ly0 = -0.5f * h1, ly1 = 0.5f * h1;
        px[0] = xc1 + lx0 * c1 - ly0 * s1;  py[0] = yc1 + lx0 * s1 + ly0 * c1;
        px[1] = xc1 + lx1 * c1 - ly0 * s1;  py[1] = yc1 + lx1 * s1 + ly0 * c1;
        px[2] = xc1 + lx1 * c1 - ly1 * s1;  py[2] = yc1 + lx1 * s1 + ly1 * c1;
        px[3] = xc1 + lx0 * c1 - ly1 * s1;  py[3] = yc1 + lx0 * s1 + ly1 * c1;
#pragma unroll
        for (int s2i = 4; s2i < CAP; ++s2i) { px[s2i] = 0.f; py[s2i] = 0.f; }
    }
    float qx[4], qy[4];
    {
        float lx0 = -0.5f * w2, lx1 = 0.5f * w2;
        float ly0 = -0.5f * h2, ly1 = 0.5f * h2;
        qx[0] = xc2 + lx0 * c2 - ly0 * s2;  qy[0] = yc2 + lx0 * s2 + ly0 * c2;
        qx[1] = xc2 + lx1 * c2 - ly0 * s2;  qy[1] = yc2 + lx1 * s2 + ly0 * c2;
        qx[2] = xc2 + lx1 * c2 - ly1 * s2;  qy[2] = yc2 + lx1 * s2 + ly1 * c2;
        qx[3] = xc2 + lx0 * c2 - ly1 * s2;  qy[3] = yc2 + lx0 * s2 + ly1 * c2;
    }

    int n = 4;
#pragma unroll
    for (int e = 0; e < 4; ++e) {
        float p0x = qx[e], p0y = qy[e];
        float ex = qx[(e + 1) & 3] - p0x, ey = qy[(e + 1) & 3] - p0y;

        float pxp = px[0], pyp = py[0];
#pragma unroll
        for (int s = 1; s < CAP; ++s)
            if (s == n - 1) { pxp = px[s]; pyp = py[s]; }
        float dp = ex * (pyp - p0y) - ey * (pxp - p0x);

        float nx_[CAP], ny_[CAP];
#pragma unroll
        for (int s = 0; s < CAP; ++s) { nx_[s] = 0.f; ny_[s] = 0.f; }
        int m = 0;

#pragma unroll
        for (int k = 0; k < CAP; ++k) {
            bool act = (k < n);
            float pxc = px[k], pyc = py[k];
            float dc = ex * (pyc - p0y) - ey * (pxc - p0x);
            bool cin = (dc >= 0.0f), pin = (dp >= 0.0f);

            float den = dp - dc;
            den = (fabsf(den) < EPSF) ? EPSF : den;
            float t = dp / den;
            float ix = pxp + t * (pxc - pxp);
            float iy = pyp + t * (pyc - pyp);

            bool emit_cross = act && (cin != pin);
            if (emit_cross) {
#pragma unroll
                for (int s = 0; s < CAP; ++s)
                    if (s == m) { nx_[s] = ix; ny_[s] = iy; }
                ++m;
            }
            bool emit_cur = act && cin;
            if (emit_cur) {
#pragma unroll
                for (int s = 0; s < CAP; ++s)
                    if (s == m) { nx_[s] = pxc; ny_[s] = pyc; }
                ++m;
            }
            if (act) { pxp = pxc; pyp = pyc; dp = dc; }
        }
        n = (m < CAP) ? m : CAP;
#pragma unroll
        for (int s = 0; s < CAP; ++s) { px[s] = nx_[s]; py[s] = ny_[s]; }
    }

    if (n < 3) return 0.0f;
    float s = 0.0f;
#pragma unroll
    for (int k = 0; k < CAP; ++k) {
        if (k < n) {
            float nxk = px[(k + 1) & (CAP - 1)];
            float nyk = py[(k + 1) & (CAP - 1)];
            if (k == n - 1) { nxk = px[0]; nyk = py[0]; }
            s += px[k] * nyk - py[k] * nxk;
        }
    }
    return 0.5f * fabsf(s);
}

// ---------------------------------------------------------------------------
// Init: fused memset + prep (verified R7). Thread t zeros mask row t,
// threads <64 zero summary, threads <n compute box8[t].
// ---------------------------------------------------------------------------
__global__ __launch_bounds__(256)
void init_kernel(const float* __restrict__ boxes, float4* __restrict__ box8,
                 ulonglong2* __restrict__ maskv,
                 unsigned long long* __restrict__ summary,
                 int n, int rows_total, int words)
{
    int t = blockIdx.x * 256 + threadIdx.x;
    if (t < rows_total) {
        ulonglong2 z; z.x = 0ULL; z.y = 0ULL;
        ulonglong2* p = maskv + (size_t)t * (words >> 1);
        for (int k = 0; k < (words >> 1); ++k) p[k] = z;
    }
    if (t < 64) summary[t] = 0ULL;
    if (t < n) {
        const float* b = boxes + (size_t)t * 5;
        float x = b[0], y = b[1], w = b[2], h = b[3], th = b[4];
        box8[2 * t]     = make_float4(x, y, w, h);
        box8[2 * t + 1] = make_float4(cosf(th), sinf(th),
                                      0.5f * sqrtf(w * w + h * h), w * h);
    }
}

// ---------------------------------------------------------------------------
// Pair kernel, tiled (verified R6/R7). Only change: no word swizzle (greedy's
// dense diagonal read is gone; rule #21 both-sides-or-neither -> neither).
// ---------------------------------------------------------------------------
__global__ __launch_bounds__(256)
void filter_kernel(const float4* __restrict__ box8,
                   unsigned long long* __restrict__ mask,
                   unsigned long long* __restrict__ summary,
                   int n, int words)
{
    const int jt = blockIdx.x, it = blockIdx.y;
    const int i0 = it * ITILE;
    if (i0 >= jt * 256 + 255) return;            // dead tile: no pair j > i
    const int j = jt * 256 + threadIdx.x;

    __shared__ float4 atile[2 * ITILE];
    __shared__ unsigned int q[QCAP];
    __shared__ int qcnt;

    if (threadIdx.x == 0) qcnt = 0;
    if (threadIdx.x < 2 * ITILE) {
        int src = 2 * i0 + threadIdx.x;
        atile[threadIdx.x] = (src < 2 * n) ? box8[src]
                                           : make_float4(0.f, 0.f, 0.f, 0.f);
    }
    __syncthreads();

    float4 B0, B1;
    bool jok = (j < n);
    if (jok) { B0 = box8[2 * j]; B1 = box8[2 * j + 1]; }
    else     { B0 = make_float4(0,0,0,0); B1 = make_float4(0,0,0,0); }

#pragma unroll
    for (int ii = 0; ii < ITILE; ++ii) {
        int i = i0 + ii;
        float4 A0 = atile[2 * ii], A1 = atile[2 * ii + 1];  // LDS broadcast
        bool pass = jok && (j > i) && (i < n);
        float dx = A0.x - B0.x, dy = A0.y - B0.y;
        float rr = A1.z + B1.z + 1e-2f;
        pass = pass && (dx * dx + dy * dy <= rr * rr);
        float amin = fminf(A1.w, B1.w), amax = fmaxf(A1.w, B1.w);
        pass = pass && (amin >= 0.699f * amax);
        if (pass) {
            int idx = atomicAdd(&qcnt, 1);       // LDS atomic, rare
            q[idx] = ((unsigned int)i << 16) | (unsigned int)j;
        }
    }
    __syncthreads();

    int qn = qcnt;                               // <= QCAP by construction
    for (int t = threadIdx.x; t < qn; t += 256) {
        unsigned int pk = q[t];
        int i2 = (int)(pk >> 16), j2 = (int)(pk & 0xffffu);
        float4 A0 = box8[2 * i2], A1 = box8[2 * i2 + 1];
        float4 C0 = box8[2 * j2], C1 = box8[2 * j2 + 1];
        float a1 = A1.w, a2 = C1.w;
        float inter = rect_inter_area_cs(A0.x, A0.y, A0.z, A0.w, A1.x, A1.y,
                                         C0.x, C0.y, C0.z, C0.w, C1.x, C1.y);
        float iou = inter / (a1 + a2 - inter + EPSF);
        if (iou >= NMS_THR) {
            atomicOr(&mask[(size_t)i2 * words + (j2 >> 6)], 1ULL << (j2 & 63));
            atomicOr(&summary[i2 >> 6], 1ULL << (i2 & 63));
        }
    }
}

__device__ __forceinline__ unsigned long long rl64(unsigned long long v, int l) {
    unsigned int lo = (unsigned int)__builtin_amdgcn_readlane((int)(unsigned int)v, l);
    unsigned int hi = (unsigned int)__builtin_amdgcn_readlane((int)(v >> 32), l);
    return ((unsigned long long)hi << 32) | lo;
}

// ---------------------------------------------------------------------------
// Greedy NMS, one wave, SPARSE: summary -> compact nonzero-row list ->
// stage only those rows into an LDS row cache (4 scattered rows per
// global_load_lds via per-lane global addresses; one vmcnt(0) total).
// Per chunk: if no candidate row is nonzero, the decision is pure ALU
// (kmask = ~cw & valid) with ZERO memory access. D-reads / OR-reads hit
// the LDS cache; rows beyond CAPR fall back to direct global reads
// (correctness path, never expected). Decision logic identical to R7.
// Assumes words<=32, chunks<=32 (n<=2048).
// ---------------------------------------------------------------------------
__global__ __launch_bounds__(64, 1)
void greedy_kernel(const unsigned long long* __restrict__ mask,
                   const unsigned long long* __restrict__ summary,
                   int* __restrict__ keep, int n, int words)
{
    __shared__ __align__(16) unsigned long long rowdat[CAPR * 32]; // 120 KB
    __shared__ unsigned int rowlist[CAPR];
    const int lane = threadIdx.x;
    const int chunks = (n + 63) >> 6;

    // lane c holds summary word of chunk c (row-nonzero bits)
    unsigned long long szv = (lane < chunks) ? summary[lane] : 0ULL;

    // exclusive prefix of nonzero-row counts per chunk (shfl inclusive scan)
    int pc = __popcll(szv);
    int pref = pc;
#pragma unroll
    for (int d = 1; d < 64; d <<= 1) {
        int t = __shfl_up(pref, d);
        if (lane >= d) pref += t;
    }
    int base_excl = pref - pc;
    int R = __shfl(pref, chunks - 1);        // total nonzero rows

    // write this chunk's nonzero rows into the compact row list
    {
        unsigned long long m = szv;
        int s = base_excl;
        while (m && s < CAPR) {
            int k = (int)__builtin_ctzll(m);
            m &= m - 1;
            rowlist[s] = (unsigned int)((lane << 6) + k);
            ++s;
        }
    }
    __syncthreads();

    // stage nonzero rows: 4 rows (1 KB) per global_load_lds instruction
    int Rc = (R < CAPR) ? R : CAPR;
    if (Rc > 0) {
        int nins = (Rc + 3) >> 2;
        for (int t = 0; t < nins; ++t) {
            int slot = (t << 2) + (lane >> 4);
            int cs = (slot < Rc) ? slot : (Rc - 1);
            unsigned int row = rowlist[cs];
            const char* src = (const char*)(mask + (size_t)row * words)
                            + (size_t)(lane & 15) * 16;
            char* dst = (char*)rowdat + (size_t)t * 1024;
            __builtin_amdgcn_global_load_lds(
                (const GLOBAL_AS unsigned int*)src,
                (LDS_AS unsigned int*)dst, 16, 0, 0);
        }
    }
    asm volatile("s_waitcnt vmcnt(0)" ::: "memory");
    __builtin_amdgcn_sched_barrier(0);

    unsigned long long acc = 0ULL;   // lane: OR of kept rows' word (lane&31)
    int cnt = 0;

    for (int c = 0; c < chunks; ++c) {
        if (cnt >= TOPN) break;
        const int base = c << 6;
        unsigned long long cw = rl64(acc, c);          // acc dup'd both halves
        unsigned long long nzc = rl64(szv, c);         // nonzero-row bits
        unsigned long long valid =
            (n - base >= 64) ? ~0ULL : ((1ULL << (n - base)) - 1ULL);
        unsigned long long cand = ~cw & valid;
        int rem = TOPN - cnt;

        unsigned long long kmask;
        if ((nzc & cand) == 0ULL && __popcll(cand) <= rem) {
            kmask = cand;                              // zero-memory fast path
        } else {
            int bexc = __builtin_amdgcn_readlane(base_excl, c);
            unsigned long long D = 0ULL;
            if ((nzc >> lane) & 1ULL) {
                int slot = bexc +
                    (int)__popcll(nzc & ((lane == 0) ? 0ULL
                                         : ((~0ULL) >> (64 - lane))));
                D = (slot < CAPR)
                    ? rowdat[(size_t)slot * 32 + c]
                    : mask[(size_t)(base + lane) * words + c];
            }
            unsigned long long intra = __ballot((D & cand) != 0ULL);
            if ((intra & cand) == 0ULL && __popcll(cand) <= rem) {
                kmask = cand;                          // parallel decision
            } else {
                kmask = 0ULL;                          // serial fallback
                int cl = cnt;
#pragma unroll
                for (int k = 0; k < 64; ++k) {
                    if (!((cw >> k) & 1ULL) && cl < TOPN && (base + k) < n) {
                        cw |= rl64(D, k);              // literal lane index
                        kmask |= (1ULL << k);
                        ++cl;
                    }
                }
            }
        }

        if ((kmask >> lane) & 1ULL)
            keep[cnt + __popcll(kmask & ((1ULL << lane) - 1ULL))] = base + lane;
        cnt += __popcll(kmask);

        // OR kept nonzero rows into distributed acc (word lane&31, dup'd)
        unsigned long long orrows = kmask & nzc;
        if (orrows) {
            int bexc = __builtin_amdgcn_readlane(base_excl, c);
            while (orrows) {
                int r = (int)__builtin_ctzll(orrows);
                orrows &= orrows - 1ULL;
                int slot = bexc +
                    (int)__popcll(nzc & ((r == 0) ? 0ULL
                                         : ((~0ULL) >> (64 - r))));
                unsigned long long v = (slot < CAPR)
                    ? rowdat[(size_t)slot * 32 + (lane & 31)]
                    : mask[(size_t)(base + r) * words + (lane & 31)];
                acc |= v;
            }
        }
    }

    // tail fill: keep[cnt..TOPN-1] = -1
    for (int t = cnt + lane; t < TOPN; t += 64) keep[t] = -1;
}

extern "C" void kernel_launch(void* const* d_in, const int* in_sizes, int n_in,
                              void* d_out, int out_size, void* d_ws, size_t ws_size,
                              hipStream_t stream) {
    const float* boxes = (const float*)d_in[0];
    int n = in_sizes[0] / 5;                     // 2048
    int words = (n + 63) / 64;                   // 32
    int chunks = (n + 63) / 64;
    int rows_total = chunks * 64;                // 2048
    int* keep = (int*)d_out;

    // ws layout: mask (rows_total*words*8) | summary (512B) | box8 (n*32B)
    unsigned long long* mask = (unsigned long long*)d_ws;
    size_t mask_alloc = (size_t)rows_total * words * 8;
    unsigned long long* summary =
        (unsigned long long*)((char*)d_ws + mask_alloc);
    float4* box8 = (float4*)((char*)d_ws + mask_alloc + 512);

    init_kernel<<<(rows_total + 255) / 256, 256, 0, stream>>>(
        boxes, box8, (ulonglong2*)mask, summary, n, rows_total, words);

    dim3 grid((n + 255) / 256, (n + ITILE - 1) / ITILE);
    filter_kernel<<<grid, 256, 0, stream>>>(box8, mask, summary, n, words);
    greedy_kernel<<<1, 64, 0, stream>>>(mask, summary, keep, n, words);
}